// Round 13
// baseline (238.264 us; speedup 1.0000x reference)
//
#include <hip/hip_runtime.h>
#include <cstdint>

#define R_TOT 16384
#define T_NT  2048
#define DD    128
#define HH    512
#define MC_   20
#define BR    16             // rows per block in k3
#define NBLK  1024           // R_TOT / BR
#define SPW   16             // 32-col steps per wave (64 total / 4 waves)

// Output layout (floats)
#define MASK_OFF 0
#define LOGP_OFF 16384
#define WORD_OFF 32768
#define CHAR_OFF 49152
#define EMB_OFF  376832          // 49152 + 16384*20
#define LOSS_OFF 2473984         // 376832 + 16384*128

// ws layout (float slots)
#define X_OFF     0              // x f32 [16384][128]
#define HDN_OFF   2097152        // hdn f32 [16384][512]
#define HDNB_OFF  10485760       // hdn bf16 ushort[16384*512]
#define WT_OFF    14680064       // wtgt f32 [2048][128]
#define WTT5_OFF  14942208       // wtgtT5 ushort[64][8][512]      (262144)
#define W2T_OFF   15204352       // W2Tf f32 [2048][512]
#define W2Q_OFF   16252928       // W2q ushort[64][2][16][512]     (1048576)
#define ENT_OFF   16777216       // 1024
#define CNT_OFF   16778240       // 1024

typedef __attribute__((ext_vector_type(8))) short short8v;
typedef __attribute__((ext_vector_type(4))) float f32x4;
typedef unsigned short ushort_t;

__device__ __forceinline__ ushort_t f2bf(float f) {
    union { float f; unsigned int u; } v; v.f = f;
    unsigned int r = v.u + 0x7FFFu + ((v.u >> 16) & 1u);
    return (ushort_t)(r >> 16);
}

// ---------------- K1: gather embeddings ----------------
__global__ __launch_bounds__(256) void k1_gather(
    const int* __restrict__ inp_word, const int* __restrict__ tgt_ids,
    const float* __restrict__ W, float* __restrict__ x, float* __restrict__ wtgt)
{
    int row = blockIdx.x * 2 + (threadIdx.x >> 7);
    int d = threadIdx.x & 127;
    if (row < R_TOT) {
        int wsrc = inp_word[row];
        x[(size_t)row * DD + d] = W[(size_t)wsrc * DD + d];
    } else {
        int rr = row - R_TOT;
        if (rr < T_NT) {
            int wsrc = tgt_ids[rr];
            wtgt[(size_t)rr * DD + d] = W[(size_t)wsrc * DD + d];
        }
    }
}

// ---------------- K1b: wtgt -> wtgtT5 full-K PV B-fragment pack ----------------
// wtgtT5[(sc*8+df)*512 + lane*8 + j] = bf16(wtgt[sc*32 + cmap][df*16 + (lane&15)])
//   cmap = j<4 ? (lane>>4)*4+j : 16 + (lane>>4)*4 + (j-4)
__global__ __launch_bounds__(256) void k1b_wtgtT5(
    const float* __restrict__ wtgt, ushort_t* __restrict__ wtgtT5)
{
    const int sc = blockIdx.x, t = threadIdx.x;
    #pragma unroll
    for (int it = 0; it < 2; ++it) {
        int idx = it * 256 + t;             // 0..511
        int df = idx >> 6, lane = idx & 63;
        int lrow = lane & 15, kg = lane >> 4;
        ushort_t* dst = wtgtT5 + ((size_t)sc * 8 + df) * 512 + lane * 8;
        #pragma unroll
        for (int j = 0; j < 8; ++j) {
            int col = sc * 32 + (j < 4 ? kg * 4 + j : 16 + kg * 4 + (j - 4));
            dst[j] = f2bf(wtgt[(size_t)col * DD + df * 16 + lrow]);
        }
    }
}

// ---------------- K0: W2 [512][2048] -> W2Tf f32 + W2q lane-linear fragment pack ----------------
// W2q[((sc*2+cs)*16+ks)*512 + lane*8 + i] = bf16(W2[ks*32 + (lane>>4)*8 + i][sc*32 + cs*16 + (lane&15)])
__global__ __launch_bounds__(256) void k0_w2t(
    const float* __restrict__ W2, float* __restrict__ W2Tf, ushort_t* __restrict__ W2q)
{
    __shared__ float tile[32][33];
    const int js = blockIdx.x, ks = blockIdx.y;
    const int cb = js * 32, kb = ks * 32;
    const int lx = threadIdx.x & 31, ly = threadIdx.x >> 5;
    #pragma unroll
    for (int i = 0; i < 32; i += 8)
        tile[ly + i][lx] = W2[(size_t)(kb + ly + i) * T_NT + cb + lx];
    __syncthreads();
    #pragma unroll
    for (int i = 0; i < 32; i += 8) {
        int c = cb + ly + i, k = kb + lx;
        W2Tf[(size_t)c * HH + k] = tile[lx][ly + i];
    }
    if (threadIdx.x < 128) {
        int c = threadIdx.x >> 2, kgrp = threadIdx.x & 3;
        int cs = c >> 4, lrow = c & 15;
        ushort_t* dst = W2q + (size_t)(((js * 2 + cs) * 16 + ks) * 512) + (kgrp * 16 + lrow) * 8;
        #pragma unroll
        for (int i = 0; i < 8; ++i)
            dst[i] = f2bf(tile[kgrp * 8 + i][c]);
    }
}

// ---------------- K2: hdn = relu(x @ W1 + b1), fp32 + bf16 outputs ----------------
__global__ __launch_bounds__(256) void k2_hdn(
    const float* __restrict__ x, const float* __restrict__ W1,
    const float* __restrict__ b1, float* __restrict__ hdn, ushort_t* __restrict__ hdnB)
{
    __shared__ float As[16][64];
    __shared__ float Bs[16][64];
    const int t = threadIdx.x;
    const int bm = blockIdx.x * 64;
    const int bn = blockIdx.y * 64;
    const int tx = t & 15, ty = t >> 4;
    float acc[4][4] = {};
    for (int k0 = 0; k0 < DD; k0 += 16) {
        {
            int m = t >> 2, kq = t & 3;
            float4 v = *(const float4*)(x + (size_t)(bm + m) * DD + k0 + kq * 4);
            As[kq * 4 + 0][m] = v.x; As[kq * 4 + 1][m] = v.y;
            As[kq * 4 + 2][m] = v.z; As[kq * 4 + 3][m] = v.w;
        }
        {
            int k = t >> 4, nq = t & 15;
            *(float4*)(&Bs[k][nq * 4]) =
                *(const float4*)(W1 + (size_t)(k0 + k) * HH + bn + nq * 4);
        }
        __syncthreads();
        #pragma unroll
        for (int k = 0; k < 16; ++k) {
            float a[4], b[4];
            #pragma unroll
            for (int i = 0; i < 4; i++) a[i] = As[k][ty * 4 + i];
            #pragma unroll
            for (int j = 0; j < 4; j++) b[j] = Bs[k][tx * 4 + j];
            #pragma unroll
            for (int i = 0; i < 4; i++)
                #pragma unroll
                for (int j = 0; j < 4; j++)
                    acc[i][j] = fmaf(a[i], b[j], acc[i][j]);
        }
        __syncthreads();
    }
    #pragma unroll
    for (int i = 0; i < 4; i++) {
        int m = bm + ty * 4 + i;
        int n = bn + tx * 4;
        float4 v;
        v.x = fmaxf(acc[i][0] + b1[n + 0], 0.f);
        v.y = fmaxf(acc[i][1] + b1[n + 1], 0.f);
        v.z = fmaxf(acc[i][2] + b1[n + 2], 0.f);
        v.w = fmaxf(acc[i][3] + b1[n + 3], 0.f);
        *(float4*)(hdn + (size_t)m * HH + n) = v;
        ushort4 hb;
        hb.x = f2bf(v.x); hb.y = f2bf(v.y); hb.z = f2bf(v.z); hb.w = f2bf(v.w);
        *(ushort4*)(hdnB + (size_t)m * HH + n) = hb;
    }
}

// ---------------- K3: 16 rows/block, 4 independent col-stream waves, no in-loop barriers ----------------
// 1024 blocks x 256 threads. Wave w: steps sc = ((blk+w)&3) + 4*((s+rot)&15), s=0..15.
// A (hdn frags) in LDS; B (W2q) + V (wtgtT5) direct from L2, lane-linear; swapped S-MFMA.
__global__ __launch_bounds__(256) void k3_fused(
    const ushort_t* __restrict__ hdnB, const float* __restrict__ hdn,
    const ushort_t* __restrict__ W2q, const float* __restrict__ W2Tf,
    const float* __restrict__ b2, const float* __restrict__ gumbel,
    const int* __restrict__ inp_word, const int* __restrict__ keyword_table,
    const int* __restrict__ tgt_ids, const int* __restrict__ lut,
    const float* __restrict__ x, const ushort_t* __restrict__ wtgtT5,
    float* __restrict__ out, float* __restrict__ entP, float* __restrict__ cntP)
{
    __shared__ float bigS[6144];       // 24 KB: A-pack (16 KB) in loop, merge scratch after
    __shared__ float statP[4][16][8];
    __shared__ int   candS[BR * 2];
    __shared__ float invs2S[BR], entS[BR];
    __shared__ int   mskS[BR];

    const int t = threadIdx.x;
    const int wid = t >> 6, lane = t & 63;
    const int lrow = lane & 15, kgrp = lane >> 4;
    const int row0 = blockIdx.x * BR;

    ushort_t* aP = (ushort_t*)bigS;    // [ks 0..15][lane][8] bf16

    // ---- A-pack: hdnB fragments -> lane-linear LDS ----
    #pragma unroll
    for (int it = 0; it < 4; ++it) {
        int gid = it * 256 + t;          // 1024 granules of 16 B
        int ks = gid >> 6, l2 = gid & 63;
        int lr = l2 & 15, kg = l2 >> 4;
        uint4 v = *(const uint4*)(hdnB + (size_t)(row0 + lr) * HH + ks * 32 + kg * 8);
        *(uint4*)(aP + gid * 8) = v;
    }
    __syncthreads();

    const int scq = (int)((blockIdx.x + wid) & 3);
    const int srot = (int)((blockIdx.x >> 2) & 15);

    const ushort_t* aRd = aP + lane * 8;
    const float* gRow = gumbel + (size_t)(row0 + lrow) * T_NT + kgrp * 4;

    // ---- scalar stats (lane owns row lrow, cols of its kgrp slice) ----
    float m_ = -1e30f, sE_ = 0.f, sEl_ = 0.f, s2_ = 0.f;
    float a1_ = -1e30f, a2_ = -1e30f;
    int i1_ = 0, i2_ = 0;
    f32x4 accpv[8];
    #pragma unroll
    for (int df = 0; df < 8; ++df) accpv[df] = (f32x4){0.f, 0.f, 0.f, 0.f};

    // step-0 gumbel prefetch
    {
        int sc00 = scq + 4 * (srot & 15);
        // fallthrough into loop with ga/gb preloaded
    }
    f32x4 ga, gb;
    {
        int sc00 = scq + 4 * (srot & 15);
        ga = *(const f32x4*)(gRow + sc00 * 32);
        gb = *(const f32x4*)(gRow + sc00 * 32 + 16);
    }

    for (int s = 0; s < SPW; ++s) {
        const int sc = scq + 4 * ((s + srot) & 15);
        const int scn = scq + 4 * ((s + 1 + srot) & 15);

        // prefetch next-step gumbel (HBM; full step of cover)
        f32x4 gna = *(const f32x4*)(gRow + scn * 32);
        f32x4 gnb = *(const f32x4*)(gRow + scn * 32 + 16);

        // b2 (L1-resident after first step)
        f32x4 b2a = *(const f32x4*)(b2 + sc * 32 + kgrp * 4);
        f32x4 b2b = *(const f32x4*)(b2 + sc * 32 + kgrp * 4 + 16);

        // S tile: two col-half chains, A=W2frag (L2), B=hdnfrag (LDS, shared read)
        const ushort_t* w2a = W2q + (size_t)sc * 16384 + lane * 8;
        f32x4 c0[4], c1[4];
        #pragma unroll
        for (int j = 0; j < 4; ++j) { c0[j] = (f32x4){0.f,0.f,0.f,0.f}; c1[j] = c0[j]; }
        #pragma unroll
        for (int ks = 0; ks < 16; ++ks) {
            short8v avk = *(const short8v*)(aRd + ks * 512);
            short8v wa0 = *(const short8v*)(w2a + ks * 512);
            short8v wa1 = *(const short8v*)(w2a + 8192 + ks * 512);
            c0[ks & 3] = __builtin_amdgcn_mfma_f32_16x16x32_bf16(wa0, avk, c0[ks & 3], 0, 0, 0);
            c1[ks & 3] = __builtin_amdgcn_mfma_f32_16x16x32_bf16(wa1, avk, c1[ks & 3], 0, 0, 0);
        }
        f32x4 acc0 = (c0[0] + c0[1]) + (c0[2] + c0[3]);
        f32x4 acc1 = (c1[0] + c1[1]) + (c1[2] + c1[3]);

        // stats + top2 + in-register P (both halves -> one full-K pav)
        short8v pav;
        const int colb = sc * 32 + kgrp * 4;
        #pragma unroll
        for (int q = 0; q < 4; ++q) {
            float l0 = acc0[q] + b2a[q];
            m_ = fmaxf(m_, l0);
            float e0 = __expf(l0);
            sE_ += e0; sEl_ = fmaf(e0, l0, sEl_);
            float aa0 = l0 + ga[q];
            float p0 = __expf(2.0f * aa0);
            s2_ += p0;
            if (aa0 > a1_) { a2_ = a1_; i2_ = i1_; a1_ = aa0; i1_ = colb + q; }
            else if (aa0 > a2_) { a2_ = aa0; i2_ = colb + q; }
            pav[q] = (short)f2bf(p0);

            float l1 = acc1[q] + b2b[q];
            m_ = fmaxf(m_, l1);
            float e1 = __expf(l1);
            sE_ += e1; sEl_ = fmaf(e1, l1, sEl_);
            float aa1 = l1 + gb[q];
            float p1 = __expf(2.0f * aa1);
            s2_ += p1;
            if (aa1 > a1_) { a2_ = a1_; i2_ = i1_; a1_ = aa1; i1_ = colb + 16 + q; }
            else if (aa1 > a2_) { a2_ = aa1; i2_ = colb + 16 + q; }
            pav[4 + q] = (short)f2bf(p1);
        }

        // PV: full K=32, 8 MFMAs; B loaded just-in-time (L2, lane-linear)
        const ushort_t* vt = wtgtT5 + (size_t)sc * 4096 + lane * 8;
        #pragma unroll
        for (int df = 0; df < 8; ++df) {
            short8v bv = *(const short8v*)(vt + df * 512);
            accpv[df] = __builtin_amdgcn_mfma_f32_16x16x32_bf16(pav, bv, accpv[df], 0, 0, 0);
        }

        ga = gna; gb = gnb;
    }

    // ---- in-wave reduction across kgrp (lanes sharing lrow) ----
    #pragma unroll
    for (int mk = 16; mk < 64; mk <<= 1) {
        m_ = fmaxf(m_, __shfl_xor(m_, mk));
        sE_ += __shfl_xor(sE_, mk);
        sEl_ += __shfl_xor(sEl_, mk);
        s2_ += __shfl_xor(s2_, mk);
        float ob1 = __shfl_xor(a1_, mk); int oj1 = __shfl_xor(i1_, mk);
        float ob2 = __shfl_xor(a2_, mk); int oj2 = __shfl_xor(i2_, mk);
        if (ob1 > a1_ || (ob1 == a1_ && oj1 < i1_)) {
            if (a1_ > ob2 || (a1_ == ob2 && i1_ < oj2)) { a2_ = a1_; i2_ = i1_; }
            else { a2_ = ob2; i2_ = oj2; }
            a1_ = ob1; i1_ = oj1;
        } else {
            if (ob1 > a2_) { a2_ = ob1; i2_ = oj1; }
        }
    }

    __syncthreads();   // all waves done with aP; scratch reuse + statP publish safe

    // ---- publish partials ----
    if (lane < 16) {
        float* st = &statP[wid][lane][0];
        st[0] = m_; st[1] = sE_; st[2] = sEl_; st[3] = s2_;
        st[4] = a1_; st[5] = __int_as_float(i1_);
        st[6] = a2_; st[7] = __int_as_float(i2_);
    }
    if (wid >= 1) {
        float* scr = bigS + (wid - 1) * 2048;
        #pragma unroll
        for (int df = 0; df < 8; ++df)
            #pragma unroll
            for (int q = 0; q < 4; ++q)
                scr[(kgrp * 4 + q) * 128 + df * 16 + lrow] = accpv[df][q];
    }
    __syncthreads();

    // ---- wave 0: merge stats + PV, write scalar outputs + x_emb ----
    if (wid == 0) {
        if (lane < 16) {
            float M = -1e30f, SE = 0.f, SEL = 0.f, S2 = 0.f;
            float A1 = -1e30f, A2 = -1e30f; int I1 = 0, I2 = 0;
            #pragma unroll
            for (int w = 0; w < 4; ++w) {
                const float* st = &statP[w][lane][0];
                float ob1 = st[4]; int oj1 = __float_as_int(st[5]);
                float ob2 = st[6]; int oj2 = __float_as_int(st[7]);
                M = fmaxf(M, st[0]); SE += st[1]; SEL += st[2]; S2 += st[3];
                if (ob1 > A1 || (ob1 == A1 && oj1 < I1)) {
                    if (A1 > ob2 || (A1 == ob2 && I1 < oj2)) { A2 = A1; I2 = I1; }
                    else { A2 = ob2; I2 = oj2; }
                    A1 = ob1; I1 = oj1;
                } else {
                    if (ob1 > A2) { A2 = ob1; I2 = oj1; }
                }
            }
            int grow = row0 + lane;
            int w_in = inp_word[grow];
            int msk = keyword_table[w_in] != 0;
            out[MASK_OFF + grow] = msk ? 1.0f : 0.0f;
            out[LOGP_OFF + grow] = msk ? M : 0.0f;
            invs2S[lane] = 1.0f / S2;
            mskS[lane] = msk;
            entS[lane] = msk ? (__logf(SE) - SEL / SE) : 0.0f;
            candS[lane * 2 + 0] = I1;
            candS[lane * 2 + 1] = I2;
        }
        #pragma unroll
        for (int df = 0; df < 8; ++df)
            #pragma unroll
            for (int q = 0; q < 4; ++q)
                accpv[df][q] += bigS[0 * 2048 + (kgrp * 4 + q) * 128 + df * 16 + lrow]
                              + bigS[1 * 2048 + (kgrp * 4 + q) * 128 + df * 16 + lrow]
                              + bigS[2 * 2048 + (kgrp * 4 + q) * 128 + df * 16 + lrow];
    }
    __syncthreads();

    if (wid == 0) {
        #pragma unroll
        for (int df = 0; df < 8; ++df) {
            #pragma unroll
            for (int q = 0; q < 4; ++q) {
                int rl = kgrp * 4 + q;
                int grow = row0 + rl;
                int d = df * 16 + lrow;
                float val = accpv[df][q] * invs2S[rl];
                if (!mskS[rl]) val = x[(size_t)grow * DD + d];
                out[EMB_OFF + (size_t)grow * DD + d] = val;
            }
        }
    }

    // ---- repair + word/char outputs: wave wid handles rows wid, wid+4, wid+8, wid+12 ----
    for (int rr = wid; rr < BR; rr += 4) {
        int grow = row0 + rr;
        int i1 = candS[rr * 2 + 0], i2 = candS[rr * 2 + 1];
        int mskr = mskS[rr];
        const float* hrow = hdn + (size_t)grow * HH;
        float4 h0 = *(const float4*)(hrow + lane * 8);
        float4 h1 = *(const float4*)(hrow + lane * 8 + 4);
        float v1, v2;
        {
            const float* wrow = W2Tf + (size_t)i1 * HH;
            float4 w0 = *(const float4*)(wrow + lane * 8);
            float4 w1 = *(const float4*)(wrow + lane * 8 + 4);
            float sdot = h0.x*w0.x + h0.y*w0.y + h0.z*w0.z + h0.w*w0.w
                       + h1.x*w1.x + h1.y*w1.y + h1.z*w1.z + h1.w*w1.w;
            #pragma unroll
            for (int mk = 1; mk < 64; mk <<= 1) sdot += __shfl_xor(sdot, mk);
            v1 = sdot + b2[i1] + gumbel[(size_t)grow * T_NT + i1];
        }
        {
            const float* wrow = W2Tf + (size_t)i2 * HH;
            float4 w0 = *(const float4*)(wrow + lane * 8);
            float4 w1 = *(const float4*)(wrow + lane * 8 + 4);
            float sdot = h0.x*w0.x + h0.y*w0.y + h0.z*w0.z + h0.w*w0.w
                       + h1.x*w1.x + h1.y*w1.y + h1.z*w1.z + h1.w*w1.w;
            #pragma unroll
            for (int mk = 1; mk < 64; mk <<= 1) sdot += __shfl_xor(sdot, mk);
            v2 = sdot + b2[i2] + gumbel[(size_t)grow * T_NT + i2];
        }
        int ibest = (v2 > v1 || (v2 == v1 && i2 < i1)) ? i2 : i1;
        int word = mskr ? tgt_ids[ibest] : inp_word[grow];
        if (lane == 0) out[WORD_OFF + grow] = (float)word;
        if (lane < MC_)
            out[CHAR_OFF + (size_t)grow * MC_ + lane] = (float)lut[(size_t)word * MC_ + lane];
    }

    if (t == 0) {
        float es = 0.f; int cs = 0;
        #pragma unroll
        for (int r = 0; r < BR; r++) { es += entS[r]; cs += mskS[r]; }
        entP[blockIdx.x] = es;
        cntP[blockIdx.x] = (float)cs;
    }
}

// ---------------- K4: final loss reduction ----------------
__global__ __launch_bounds__(256) void k4_loss(
    const float* __restrict__ entP, const float* __restrict__ cntP, float* __restrict__ out)
{
    __shared__ float sE[256], sC[256];
    int t = threadIdx.x;
    float e = 0.f, c = 0.f;
    for (int i = t; i < NBLK; i += 256) { e += entP[i]; c += cntP[i]; }
    sE[t] = e; sC[t] = c;
    __syncthreads();
    for (int s = 128; s > 0; s >>= 1) {
        if (t < s) { sE[t] += sE[t + s]; sC[t] += sC[t + s]; }
        __syncthreads();
    }
    if (t == 0) {
        float ns = fmaxf(sC[0], 1.0f);
        out[LOSS_OFF] = 0.03f * sE[0] / ns;
    }
}

// ---------------- launch ----------------
extern "C" void kernel_launch(void* const* d_in, const int* in_sizes, int n_in,
                              void* d_out, int out_size, void* d_ws, size_t ws_size,
                              hipStream_t stream) {
    const int* inp_word = (const int*)d_in[0];
    const int* keyword_table = (const int*)d_in[3];
    const int* tgt_ids = (const int*)d_in[4];
    const int* lut = (const int*)d_in[5];
    const float* gumbel = (const float*)d_in[6];
    const float* W = (const float*)d_in[7];
    const float* W1 = (const float*)d_in[8];
    const float* b1 = (const float*)d_in[9];
    const float* W2 = (const float*)d_in[10];
    const float* b2 = (const float*)d_in[11];
    float* out = (float*)d_out;

    float* wsf = (float*)d_ws;
    float* x = wsf + X_OFF;
    float* hdn = wsf + HDN_OFF;
    ushort_t* hdnB = (ushort_t*)(wsf + HDNB_OFF);
    float* wtgt = wsf + WT_OFF;
    ushort_t* wtgtT5 = (ushort_t*)(wsf + WTT5_OFF);
    float* W2Tf = wsf + W2T_OFF;
    ushort_t* W2q = (ushort_t*)(wsf + W2Q_OFF);
    float* entP = wsf + ENT_OFF;
    float* cntP = wsf + CNT_OFF;

    k1_gather<<<(R_TOT + T_NT) / 2, 256, 0, stream>>>(inp_word, tgt_ids, W, x, wtgt);
    k1b_wtgtT5<<<64, 256, 0, stream>>>(wtgt, wtgtT5);
    k0_w2t<<<dim3(T_NT / 32, HH / 32), 256, 0, stream>>>(W2, W2Tf, W2q);
    k2_hdn<<<dim3(R_TOT / 64, HH / 64), 256, 0, stream>>>(x, W1, b1, hdn, hdnB);
    k3_fused<<<NBLK, 256, 0, stream>>>(hdnB, hdn, W2q, W2Tf, b2, gumbel,
                                       inp_word, keyword_table, tgt_ids, lut,
                                       x, wtgtT5, out, entP, cntP);
    k4_loss<<<1, 256, 0, stream>>>(entP, cntP, out);
}

// Round 14
// 196.205 us; speedup vs baseline: 1.2144x; 1.2144x over previous
//
#include <hip/hip_runtime.h>
#include <cstdint>

#define R_TOT 16384
#define T_NT  2048
#define DD    128
#define HH    512
#define MC_   20
#define BR    16             // rows per block in k3
#define NBLK  1024           // R_TOT / BR
#define SPW   16             // 32-col steps per wave (64 total / 4 waves)

// Output layout (floats)
#define MASK_OFF 0
#define LOGP_OFF 16384
#define WORD_OFF 32768
#define CHAR_OFF 49152
#define EMB_OFF  376832          // 49152 + 16384*20
#define LOSS_OFF 2473984         // 376832 + 16384*128

// ws layout (float slots)
#define X_OFF     0              // x f32 [16384][128]
#define HDN_OFF   2097152        // hdn f32 [16384][512]
#define HDNB_OFF  10485760       // hdn bf16 ushort[16384*512]
#define WT_OFF    14680064       // wtgt f32 [2048][128]
#define WTT5_OFF  14942208       // wtgtT5 ushort[64][8][512]      (262144)
#define W2T_OFF   15204352       // W2Tf f32 [2048][512]
#define W2Q_OFF   16252928       // W2q ushort[64][2][16][512]     (1048576)
#define ENT_OFF   16777216       // 1024
#define CNT_OFF   16778240       // 1024

typedef __attribute__((ext_vector_type(8))) short short8v;
typedef __attribute__((ext_vector_type(4))) float f32x4;
typedef unsigned short ushort_t;

__device__ __forceinline__ ushort_t f2bf(float f) {
    union { float f; unsigned int u; } v; v.f = f;
    unsigned int r = v.u + 0x7FFFu + ((v.u >> 16) & 1u);
    return (ushort_t)(r >> 16);
}

// ---------------- K1: gather embeddings ----------------
__global__ __launch_bounds__(256) void k1_gather(
    const int* __restrict__ inp_word, const int* __restrict__ tgt_ids,
    const float* __restrict__ W, float* __restrict__ x, float* __restrict__ wtgt)
{
    int row = blockIdx.x * 2 + (threadIdx.x >> 7);
    int d = threadIdx.x & 127;
    if (row < R_TOT) {
        int wsrc = inp_word[row];
        x[(size_t)row * DD + d] = W[(size_t)wsrc * DD + d];
    } else {
        int rr = row - R_TOT;
        if (rr < T_NT) {
            int wsrc = tgt_ids[rr];
            wtgt[(size_t)rr * DD + d] = W[(size_t)wsrc * DD + d];
        }
    }
}

// ---------------- K1b: wtgt -> wtgtT5 full-K PV B-fragment pack ----------------
// wtgtT5[(sc*8+df)*512 + lane*8 + j] = bf16(wtgt[sc*32 + cmap][df*16 + (lane&15)])
//   cmap = j<4 ? (lane>>4)*4+j : 16 + (lane>>4)*4 + (j-4)
__global__ __launch_bounds__(256) void k1b_wtgtT5(
    const float* __restrict__ wtgt, ushort_t* __restrict__ wtgtT5)
{
    const int sc = blockIdx.x, t = threadIdx.x;
    #pragma unroll
    for (int it = 0; it < 2; ++it) {
        int idx = it * 256 + t;             // 0..511
        int df = idx >> 6, lane = idx & 63;
        int lrow = lane & 15, kg = lane >> 4;
        ushort_t* dst = wtgtT5 + ((size_t)sc * 8 + df) * 512 + lane * 8;
        #pragma unroll
        for (int j = 0; j < 8; ++j) {
            int col = sc * 32 + (j < 4 ? kg * 4 + j : 16 + kg * 4 + (j - 4));
            dst[j] = f2bf(wtgt[(size_t)col * DD + df * 16 + lrow]);
        }
    }
}

// ---------------- K0: W2 [512][2048] -> W2Tf f32 + W2q lane-linear fragment pack ----------------
// W2q[((sc*2+cs)*16+ks)*512 + lane*8 + i] = bf16(W2[ks*32 + (lane>>4)*8 + i][sc*32 + cs*16 + (lane&15)])
__global__ __launch_bounds__(256) void k0_w2t(
    const float* __restrict__ W2, float* __restrict__ W2Tf, ushort_t* __restrict__ W2q)
{
    __shared__ float tile[32][33];
    const int js = blockIdx.x, ks = blockIdx.y;
    const int cb = js * 32, kb = ks * 32;
    const int lx = threadIdx.x & 31, ly = threadIdx.x >> 5;
    #pragma unroll
    for (int i = 0; i < 32; i += 8)
        tile[ly + i][lx] = W2[(size_t)(kb + ly + i) * T_NT + cb + lx];
    __syncthreads();
    #pragma unroll
    for (int i = 0; i < 32; i += 8) {
        int c = cb + ly + i, k = kb + lx;
        W2Tf[(size_t)c * HH + k] = tile[lx][ly + i];
    }
    if (threadIdx.x < 128) {
        int c = threadIdx.x >> 2, kgrp = threadIdx.x & 3;
        int cs = c >> 4, lrow = c & 15;
        ushort_t* dst = W2q + (size_t)(((js * 2 + cs) * 16 + ks) * 512) + (kgrp * 16 + lrow) * 8;
        #pragma unroll
        for (int i = 0; i < 8; ++i)
            dst[i] = f2bf(tile[kgrp * 8 + i][c]);
    }
}

// ---------------- K2: hdn = relu(x @ W1 + b1), fp32 + bf16 outputs ----------------
__global__ __launch_bounds__(256) void k2_hdn(
    const float* __restrict__ x, const float* __restrict__ W1,
    const float* __restrict__ b1, float* __restrict__ hdn, ushort_t* __restrict__ hdnB)
{
    __shared__ float As[16][64];
    __shared__ float Bs[16][64];
    const int t = threadIdx.x;
    const int bm = blockIdx.x * 64;
    const int bn = blockIdx.y * 64;
    const int tx = t & 15, ty = t >> 4;
    float acc[4][4] = {};
    for (int k0 = 0; k0 < DD; k0 += 16) {
        {
            int m = t >> 2, kq = t & 3;
            float4 v = *(const float4*)(x + (size_t)(bm + m) * DD + k0 + kq * 4);
            As[kq * 4 + 0][m] = v.x; As[kq * 4 + 1][m] = v.y;
            As[kq * 4 + 2][m] = v.z; As[kq * 4 + 3][m] = v.w;
        }
        {
            int k = t >> 4, nq = t & 15;
            *(float4*)(&Bs[k][nq * 4]) =
                *(const float4*)(W1 + (size_t)(k0 + k) * HH + bn + nq * 4);
        }
        __syncthreads();
        #pragma unroll
        for (int k = 0; k < 16; ++k) {
            float a[4], b[4];
            #pragma unroll
            for (int i = 0; i < 4; i++) a[i] = As[k][ty * 4 + i];
            #pragma unroll
            for (int j = 0; j < 4; j++) b[j] = Bs[k][tx * 4 + j];
            #pragma unroll
            for (int i = 0; i < 4; i++)
                #pragma unroll
                for (int j = 0; j < 4; j++)
                    acc[i][j] = fmaf(a[i], b[j], acc[i][j]);
        }
        __syncthreads();
    }
    #pragma unroll
    for (int i = 0; i < 4; i++) {
        int m = bm + ty * 4 + i;
        int n = bn + tx * 4;
        float4 v;
        v.x = fmaxf(acc[i][0] + b1[n + 0], 0.f);
        v.y = fmaxf(acc[i][1] + b1[n + 1], 0.f);
        v.z = fmaxf(acc[i][2] + b1[n + 2], 0.f);
        v.w = fmaxf(acc[i][3] + b1[n + 3], 0.f);
        *(float4*)(hdn + (size_t)m * HH + n) = v;
        ushort4 hb;
        hb.x = f2bf(v.x); hb.y = f2bf(v.y); hb.z = f2bf(v.z); hb.w = f2bf(v.w);
        *(ushort4*)(hdnB + (size_t)m * HH + n) = hb;
    }
}

// ---------------- K3: 16 rows/block, 4 independent col-stream waves, no in-loop barriers ----------------
// 1024 blocks x 256 threads. Wave w: steps sc = ((blk+w)&3) + 4*s, s=0..15.
// A (hdn frags) in LDS; B (W2q) + V (wtgtT5) direct from L2, lane-linear; swapped S-MFMA.
// Register budget target: <=170 total (3 waves/SIMD): S-acc 16 + PV-acc 32 + ~110 arch.
__global__ __launch_bounds__(256) void k3_fused(
    const ushort_t* __restrict__ hdnB, const float* __restrict__ hdn,
    const ushort_t* __restrict__ W2q, const float* __restrict__ W2Tf,
    const float* __restrict__ b2, const float* __restrict__ gumbel,
    const int* __restrict__ inp_word, const int* __restrict__ keyword_table,
    const int* __restrict__ tgt_ids, const int* __restrict__ lut,
    const float* __restrict__ x, const ushort_t* __restrict__ wtgtT5,
    float* __restrict__ out, float* __restrict__ entP, float* __restrict__ cntP)
{
    __shared__ float bigS[6144];       // 24 KB: A-pack (16 KB) in loop, merge scratch after
    __shared__ float statP[4][16][8];
    __shared__ int   candS[BR * 2];
    __shared__ float invs2S[BR], entS[BR];
    __shared__ int   mskS[BR];

    const int t = threadIdx.x;
    const int wid = t >> 6, lane = t & 63;
    const int lrow = lane & 15, kgrp = lane >> 4;
    const int row0 = blockIdx.x * BR;

    ushort_t* aP = (ushort_t*)bigS;    // [ks 0..15][lane][8] bf16

    // ---- A-pack: hdnB fragments -> lane-linear LDS ----
    #pragma unroll
    for (int it = 0; it < 4; ++it) {
        int gid = it * 256 + t;          // 1024 granules of 16 B
        int ks = gid >> 6, l2 = gid & 63;
        int lr = l2 & 15, kg = l2 >> 4;
        uint4 v = *(const uint4*)(hdnB + (size_t)(row0 + lr) * HH + ks * 32 + kg * 8);
        *(uint4*)(aP + gid * 8) = v;
    }
    __syncthreads();

    const int scq = (int)((blockIdx.x + wid) & 3);

    const ushort_t* aRd = aP + lane * 8;
    const float* gRow = gumbel + (size_t)(row0 + lrow) * T_NT + kgrp * 4;

    // ---- scalar stats (lane owns row lrow, cols of its kgrp slice) ----
    float m_ = -1e30f, sE_ = 0.f, sEl_ = 0.f, s2_ = 0.f;
    float a1_ = -1e30f, a2_ = -1e30f;
    int i1_ = 0, i2_ = 0;
    f32x4 accpv[8];
    #pragma unroll
    for (int df = 0; df < 8; ++df) accpv[df] = (f32x4){0.f, 0.f, 0.f, 0.f};

    // step-0 gumbel prefetch
    f32x4 ga = *(const f32x4*)(gRow + scq * 32);
    f32x4 gb = *(const f32x4*)(gRow + scq * 32 + 16);

    for (int s = 0; s < SPW; ++s) {
        const int sc = scq + 4 * s;
        const int scn = scq + 4 * ((s + 1) & 15);   // wraps to scq at last step (harmless re-read)

        // prefetch next-step gumbel (HBM; full step of cover)
        f32x4 gna = *(const f32x4*)(gRow + scn * 32);
        f32x4 gnb = *(const f32x4*)(gRow + scn * 32 + 16);

        // b2 (L1-resident after first step)
        f32x4 b2a = *(const f32x4*)(b2 + sc * 32 + kgrp * 4);
        f32x4 b2b = *(const f32x4*)(b2 + sc * 32 + kgrp * 4 + 16);

        // S tile: two col-half x two chains, A=W2frag (L2), B=hdnfrag (LDS, shared read)
        const ushort_t* w2a = W2q + (size_t)sc * 16384 + lane * 8;
        f32x4 c0a = (f32x4){0.f,0.f,0.f,0.f}, c0b = c0a, c1a = c0a, c1b = c0a;
        #pragma unroll
        for (int ks = 0; ks < 16; ks += 2) {
            short8v avk0 = *(const short8v*)(aRd + (ks + 0) * 512);
            short8v avk1 = *(const short8v*)(aRd + (ks + 1) * 512);
            c0a = __builtin_amdgcn_mfma_f32_16x16x32_bf16(*(const short8v*)(w2a + (ks+0)*512), avk0, c0a, 0, 0, 0);
            c1a = __builtin_amdgcn_mfma_f32_16x16x32_bf16(*(const short8v*)(w2a + 8192 + (ks+0)*512), avk0, c1a, 0, 0, 0);
            c0b = __builtin_amdgcn_mfma_f32_16x16x32_bf16(*(const short8v*)(w2a + (ks+1)*512), avk1, c0b, 0, 0, 0);
            c1b = __builtin_amdgcn_mfma_f32_16x16x32_bf16(*(const short8v*)(w2a + 8192 + (ks+1)*512), avk1, c1b, 0, 0, 0);
        }
        f32x4 acc0 = c0a + c0b;
        f32x4 acc1 = c1a + c1b;

        // PV B-frags for this step (issue before stats; consumed after)
        const ushort_t* vt = wtgtT5 + (size_t)sc * 4096 + lane * 8;
        short8v bvf[8];
        #pragma unroll
        for (int df = 0; df < 8; ++df) bvf[df] = *(const short8v*)(vt + df * 512);

        // stats + top2 + in-register P (both halves -> one full-K pav)
        short8v pav;
        const int colb = sc * 32 + kgrp * 4;
        #pragma unroll
        for (int q = 0; q < 4; ++q) {
            float l0 = acc0[q] + b2a[q];
            m_ = fmaxf(m_, l0);
            float e0 = __expf(l0);
            sE_ += e0; sEl_ = fmaf(e0, l0, sEl_);
            float aa0 = l0 + ga[q];
            float p0 = __expf(2.0f * aa0);
            s2_ += p0;
            if (aa0 > a1_) { a2_ = a1_; i2_ = i1_; a1_ = aa0; i1_ = colb + q; }
            else if (aa0 > a2_) { a2_ = aa0; i2_ = colb + q; }
            pav[q] = (short)f2bf(p0);

            float l1 = acc1[q] + b2b[q];
            m_ = fmaxf(m_, l1);
            float e1 = __expf(l1);
            sE_ += e1; sEl_ = fmaf(e1, l1, sEl_);
            float aa1 = l1 + gb[q];
            float p1 = __expf(2.0f * aa1);
            s2_ += p1;
            if (aa1 > a1_) { a2_ = a1_; i2_ = i1_; a1_ = aa1; i1_ = colb + 16 + q; }
            else if (aa1 > a2_) { a2_ = aa1; i2_ = colb + 16 + q; }
            pav[4 + q] = (short)f2bf(p1);
        }

        // PV: full K=32, 8 MFMAs
        #pragma unroll
        for (int df = 0; df < 8; ++df)
            accpv[df] = __builtin_amdgcn_mfma_f32_16x16x32_bf16(pav, bvf[df], accpv[df], 0, 0, 0);

        ga = gna; gb = gnb;
    }

    // ---- in-wave reduction across kgrp (lanes sharing lrow) ----
    #pragma unroll
    for (int mk = 16; mk < 64; mk <<= 1) {
        m_ = fmaxf(m_, __shfl_xor(m_, mk));
        sE_ += __shfl_xor(sE_, mk);
        sEl_ += __shfl_xor(sEl_, mk);
        s2_ += __shfl_xor(s2_, mk);
        float ob1 = __shfl_xor(a1_, mk); int oj1 = __shfl_xor(i1_, mk);
        float ob2 = __shfl_xor(a2_, mk); int oj2 = __shfl_xor(i2_, mk);
        if (ob1 > a1_ || (ob1 == a1_ && oj1 < i1_)) {
            if (a1_ > ob2 || (a1_ == ob2 && i1_ < oj2)) { a2_ = a1_; i2_ = i1_; }
            else { a2_ = ob2; i2_ = oj2; }
            a1_ = ob1; i1_ = oj1;
        } else {
            if (ob1 > a2_) { a2_ = ob1; i2_ = oj1; }
        }
    }

    __syncthreads();   // all waves done with aP; scratch reuse + statP publish safe

    // ---- publish partials ----
    if (lane < 16) {
        float* st = &statP[wid][lane][0];
        st[0] = m_; st[1] = sE_; st[2] = sEl_; st[3] = s2_;
        st[4] = a1_; st[5] = __int_as_float(i1_);
        st[6] = a2_; st[7] = __int_as_float(i2_);
    }
    if (wid >= 1) {
        float* scr = bigS + (wid - 1) * 2048;
        #pragma unroll
        for (int df = 0; df < 8; ++df)
            #pragma unroll
            for (int q = 0; q < 4; ++q)
                scr[(kgrp * 4 + q) * 128 + df * 16 + lrow] = accpv[df][q];
    }
    __syncthreads();

    // ---- wave 0: merge stats + PV, write scalar outputs + x_emb ----
    if (wid == 0) {
        if (lane < 16) {
            float M = -1e30f, SE = 0.f, SEL = 0.f, S2 = 0.f;
            float A1 = -1e30f, A2 = -1e30f; int I1 = 0, I2 = 0;
            #pragma unroll
            for (int w = 0; w < 4; ++w) {
                const float* st = &statP[w][lane][0];
                float ob1 = st[4]; int oj1 = __float_as_int(st[5]);
                float ob2 = st[6]; int oj2 = __float_as_int(st[7]);
                M = fmaxf(M, st[0]); SE += st[1]; SEL += st[2]; S2 += st[3];
                if (ob1 > A1 || (ob1 == A1 && oj1 < I1)) {
                    if (A1 > ob2 || (A1 == ob2 && I1 < oj2)) { A2 = A1; I2 = I1; }
                    else { A2 = ob2; I2 = oj2; }
                    A1 = ob1; I1 = oj1;
                } else {
                    if (ob1 > A2) { A2 = ob1; I2 = oj1; }
                }
            }
            int grow = row0 + lane;
            int w_in = inp_word[grow];
            int msk = keyword_table[w_in] != 0;
            out[MASK_OFF + grow] = msk ? 1.0f : 0.0f;
            out[LOGP_OFF + grow] = msk ? M : 0.0f;
            invs2S[lane] = 1.0f / S2;
            mskS[lane] = msk;
            entS[lane] = msk ? (__logf(SE) - SEL / SE) : 0.0f;
            candS[lane * 2 + 0] = I1;
            candS[lane * 2 + 1] = I2;
        }
        #pragma unroll
        for (int df = 0; df < 8; ++df)
            #pragma unroll
            for (int q = 0; q < 4; ++q)
                accpv[df][q] += bigS[0 * 2048 + (kgrp * 4 + q) * 128 + df * 16 + lrow]
                              + bigS[1 * 2048 + (kgrp * 4 + q) * 128 + df * 16 + lrow]
                              + bigS[2 * 2048 + (kgrp * 4 + q) * 128 + df * 16 + lrow];
    }
    __syncthreads();

    if (wid == 0) {
        #pragma unroll
        for (int df = 0; df < 8; ++df) {
            #pragma unroll
            for (int q = 0; q < 4; ++q) {
                int rl = kgrp * 4 + q;
                int grow = row0 + rl;
                int d = df * 16 + lrow;
                float val = accpv[df][q] * invs2S[rl];
                if (!mskS[rl]) val = x[(size_t)grow * DD + d];
                out[EMB_OFF + (size_t)grow * DD + d] = val;
            }
        }
    }

    // ---- repair + word/char outputs: wave wid handles rows wid, wid+4, wid+8, wid+12 ----
    for (int rr = wid; rr < BR; rr += 4) {
        int grow = row0 + rr;
        int i1 = candS[rr * 2 + 0], i2 = candS[rr * 2 + 1];
        int mskr = mskS[rr];
        const float* hrow = hdn + (size_t)grow * HH;
        float4 h0 = *(const float4*)(hrow + lane * 8);
        float4 h1 = *(const float4*)(hrow + lane * 8 + 4);
        float v1, v2;
        {
            const float* wrow = W2Tf + (size_t)i1 * HH;
            float4 w0 = *(const float4*)(wrow + lane * 8);
            float4 w1 = *(const float4*)(wrow + lane * 8 + 4);
            float sdot = h0.x*w0.x + h0.y*w0.y + h0.z*w0.z + h0.w*w0.w
                       + h1.x*w1.x + h1.y*w1.y + h1.z*w1.z + h1.w*w1.w;
            #pragma unroll
            for (int mk = 1; mk < 64; mk <<= 1) sdot += __shfl_xor(sdot, mk);
            v1 = sdot + b2[i1] + gumbel[(size_t)grow * T_NT + i1];
        }
        {
            const float* wrow = W2Tf + (size_t)i2 * HH;
            float4 w0 = *(const float4*)(wrow + lane * 8);
            float4 w1 = *(const float4*)(wrow + lane * 8 + 4);
            float sdot = h0.x*w0.x + h0.y*w0.y + h0.z*w0.z + h0.w*w0.w
                       + h1.x*w1.x + h1.y*w1.y + h1.z*w1.z + h1.w*w1.w;
            #pragma unroll
            for (int mk = 1; mk < 64; mk <<= 1) sdot += __shfl_xor(sdot, mk);
            v2 = sdot + b2[i2] + gumbel[(size_t)grow * T_NT + i2];
        }
        int ibest = (v2 > v1 || (v2 == v1 && i2 < i1)) ? i2 : i1;
        int word = mskr ? tgt_ids[ibest] : inp_word[grow];
        if (lane == 0) out[WORD_OFF + grow] = (float)word;
        if (lane < MC_)
            out[CHAR_OFF + (size_t)grow * MC_ + lane] = (float)lut[(size_t)word * MC_ + lane];
    }

    if (t == 0) {
        float es = 0.f; int cs = 0;
        #pragma unroll
        for (int r = 0; r < BR; r++) { es += entS[r]; cs += mskS[r]; }
        entP[blockIdx.x] = es;
        cntP[blockIdx.x] = (float)cs;
    }
}

// ---------------- K4: final loss reduction ----------------
__global__ __launch_bounds__(256) void k4_loss(
    const float* __restrict__ entP, const float* __restrict__ cntP, float* __restrict__ out)
{
    __shared__ float sE[256], sC[256];
    int t = threadIdx.x;
    float e = 0.f, c = 0.f;
    for (int i = t; i < NBLK; i += 256) { e += entP[i]; c += cntP[i]; }
    sE[t] = e; sC[t] = c;
    __syncthreads();
    for (int s = 128; s > 0; s >>= 1) {
        if (t < s) { sE[t] += sE[t + s]; sC[t] += sC[t + s]; }
        __syncthreads();
    }
    if (t == 0) {
        float ns = fmaxf(sC[0], 1.0f);
        out[LOSS_OFF] = 0.03f * sE[0] / ns;
    }
}

// ---------------- launch ----------------
extern "C" void kernel_launch(void* const* d_in, const int* in_sizes, int n_in,
                              void* d_out, int out_size, void* d_ws, size_t ws_size,
                              hipStream_t stream) {
    const int* inp_word = (const int*)d_in[0];
    const int* keyword_table = (const int*)d_in[3];
    const int* tgt_ids = (const int*)d_in[4];
    const int* lut = (const int*)d_in[5];
    const float* gumbel = (const float*)d_in[6];
    const float* W = (const float*)d_in[7];
    const float* W1 = (const float*)d_in[8];
    const float* b1 = (const float*)d_in[9];
    const float* W2 = (const float*)d_in[10];
    const float* b2 = (const float*)d_in[11];
    float* out = (float*)d_out;

    float* wsf = (float*)d_ws;
    float* x = wsf + X_OFF;
    float* hdn = wsf + HDN_OFF;
    ushort_t* hdnB = (ushort_t*)(wsf + HDNB_OFF);
    float* wtgt = wsf + WT_OFF;
    ushort_t* wtgtT5 = (ushort_t*)(wsf + WTT5_OFF);
    float* W2Tf = wsf + W2T_OFF;
    ushort_t* W2q = (ushort_t*)(wsf + W2Q_OFF);
    float* entP = wsf + ENT_OFF;
    float* cntP = wsf + CNT_OFF;

    k1_gather<<<(R_TOT + T_NT) / 2, 256, 0, stream>>>(inp_word, tgt_ids, W, x, wtgt);
    k1b_wtgtT5<<<64, 256, 0, stream>>>(wtgt, wtgtT5);
    k0_w2t<<<dim3(T_NT / 32, HH / 32), 256, 0, stream>>>(W2, W2Tf, W2q);
    k2_hdn<<<dim3(R_TOT / 64, HH / 64), 256, 0, stream>>>(x, W1, b1, hdn, hdnB);
    k3_fused<<<NBLK, 256, 0, stream>>>(hdnB, hdn, W2q, W2Tf, b2, gumbel,
                                       inp_word, keyword_table, tgt_ids, lut,
                                       x, wtgtT5, out, entP, cntP);
    k4_loss<<<1, 256, 0, stream>>>(entP, cntP, out);
}